// Round 11
// baseline (242.571 us; speedup 1.0000x reference)
//
#include <hip/hip_runtime.h>
#include <hip/hip_bf16.h>
#include <math.h>

#define D_MODEL 1024
#define NH      16
#define HD      64
#define T_SEQ   2048
#define B_SZ    4
#define M_ROWS  (B_SZ * T_SEQ)       // 8192
#define N_QKV   (3 * D_MODEL)        // 3072

typedef __bf16 bf16x8 __attribute__((ext_vector_type(8)));
typedef __bf16 bf16x4 __attribute__((ext_vector_type(4)));
typedef float  f32x4  __attribute__((ext_vector_type(4)));

__device__ __forceinline__ bf16x8 cvt8(float4 a, float4 b) {
    bf16x8 v;
    v[0]=(__bf16)a.x; v[1]=(__bf16)a.y; v[2]=(__bf16)a.z; v[3]=(__bf16)a.w;
    v[4]=(__bf16)b.x; v[5]=(__bf16)b.y; v[6]=(__bf16)b.z; v[7]=(__bf16)b.w;
    return v;
}

__device__ __forceinline__ void gload_lds16(const __bf16* g, __bf16* l) {
    __builtin_amdgcn_global_load_lds(
        (const __attribute__((address_space(1))) void*)g,
        (__attribute__((address_space(3))) void*)l, 16, 0, 0);
}

// raw v_exp_f32: computes 2^x (input already in log2 units)
__device__ __forceinline__ float exp2v(float x) {
    float r;
    asm("v_exp_f32 %0, %1" : "=v"(r) : "v"(x));
    return r;
}

// ---------------------------------------------------------------------------
// fp32 -> bf16 elementwise convert
// ---------------------------------------------------------------------------
__global__ __launch_bounds__(256) void cvt_bf16(const float* __restrict__ in,
                                                __bf16* __restrict__ out, int n8)
{
    int i = blockIdx.x * 256 + threadIdx.x;
    if (i < n8) {
        float4 a = ((const float4*)in)[2 * i];
        float4 b = ((const float4*)in)[2 * i + 1];
        ((bf16x8*)out)[i] = cvt8(a, b);
    }
}

// ---------------------------------------------------------------------------
// Transpose + convert: W[R][C] fp32 -> WT[C][R] bf16
// ---------------------------------------------------------------------------
__global__ __launch_bounds__(256) void transpose_cvt(
    const float* __restrict__ W, __bf16* __restrict__ WT, int R, int C)
{
    __shared__ float t[32][33];
    const int tr0 = blockIdx.y * 32, tc0 = blockIdx.x * 32;
    const int lr = threadIdx.x >> 5, lc = threadIdx.x & 31;
    #pragma unroll
    for (int i = 0; i < 4; ++i)
        t[lr + i * 8][lc] = W[(size_t)(tr0 + lr + i * 8) * C + tc0 + lc];
    __syncthreads();
    #pragma unroll
    for (int i = 0; i < 4; ++i)
        WT[(size_t)(tc0 + lr + i * 8) * R + tr0 + lc] = (__bf16)t[lc][lr + i * 8];
}

// ---------------------------------------------------------------------------
// bf16 MFMA GEMM (unchanged): 128x128 tile, BK=64, both-sides XOR swizzle.
// ---------------------------------------------------------------------------
template<int MODE>
__global__ __launch_bounds__(256) void gemm_mfma(
    const __bf16* __restrict__ A, const __bf16* __restrict__ BT,
    const float* __restrict__ bias, void* __restrict__ C0,
    __bf16* __restrict__ vT, int M, int N, int K)
{
    __shared__ __bf16 As[128 * 64];
    __shared__ __bf16 Bs[128 * 64];

    const int nbn = N >> 7;
    const int nwg = gridDim.x;
    int bid = blockIdx.x;
    bid = (bid & 7) * (nwg >> 3) + (bid >> 3);       // XCD swizzle (nwg % 8 == 0)
    const int tm = bid / nbn, tn = bid % nbn;
    const int row0 = tm << 7, col0 = tn << 7;

    const int tid  = threadIdx.x;
    const int wid  = tid >> 6, lane = tid & 63;
    const int wm   = wid >> 1, wn = wid & 1;
    const int g    = lane >> 4, r16 = lane & 15;

    f32x4 acc[4][4] = {};

    for (int k0 = 0; k0 < K; k0 += 64) {
        #pragma unroll
        for (int i = 0; i < 4; ++i) {
            const int seg = wid * 4 + i;                 // 0..15
            const int row = seg * 8 + (lane >> 3);       // 0..127
            const int kel = ((lane & 7) * 8) ^ ((row & 7) * 8);
            gload_lds16(A  + (size_t)(row0 + row) * K + k0 + kel, As + seg * 512);
            gload_lds16(BT + (size_t)(col0 + row) * K + k0 + kel, Bs + seg * 512);
        }
        __syncthreads();

        #pragma unroll
        for (int kk = 0; kk < 2; ++kk) {
            bf16x8 af[4], bfr[4];
            #pragma unroll
            for (int mt = 0; mt < 4; ++mt) {
                const int row = wm * 64 + mt * 16 + r16;
                af[mt] = *(const bf16x8*)((const char*)As + row * 128
                             + ((kk * 64 + g * 16) ^ ((row & 7) << 4)));
            }
            #pragma unroll
            for (int nt = 0; nt < 4; ++nt) {
                const int row = wn * 64 + nt * 16 + r16;
                bfr[nt] = *(const bf16x8*)((const char*)Bs + row * 128
                             + ((kk * 64 + g * 16) ^ ((row & 7) << 4)));
            }
            #pragma unroll
            for (int mt = 0; mt < 4; ++mt)
                #pragma unroll
                for (int nt = 0; nt < 4; ++nt)
                    acc[mt][nt] = __builtin_amdgcn_mfma_f32_16x16x32_bf16(
                        af[mt], bfr[nt], acc[mt][nt], 0, 0, 0);
        }
        __syncthreads();
    }

    const bool isV = (MODE == 1) && (tn >= 16);

    #pragma unroll
    for (int mt = 0; mt < 4; ++mt) {
        #pragma unroll
        for (int nt = 0; nt < 4; ++nt) {
            const int col = col0 + wn * 64 + nt * 16 + r16;
            const float bv = bias[col];
            const int rowb = row0 + wm * 64 + mt * 16 + g * 4;
            if (MODE == 0) {
                #pragma unroll
                for (int j = 0; j < 4; ++j)
                    ((float*)C0)[(size_t)(rowb + j) * N + col] = acc[mt][nt][j] + bv;
            } else if (!isV) {
                #pragma unroll
                for (int j = 0; j < 4; ++j)
                    ((__bf16*)C0)[(size_t)(rowb + j) * 2048 + col] =
                        (__bf16)(acc[mt][nt][j] + bv);
            } else {
                const int hh = (col - 2048) >> 6, dd = (col - 2048) & 63;
                const int bb = rowb >> 11, tt = rowb & 2047;
                __bf16 p4[4];
                #pragma unroll
                for (int j = 0; j < 4; ++j) p4[j] = (__bf16)(acc[mt][nt][j] + bv);
                *(bf16x4*)&vT[((size_t)((bb * NH + hh) * HD + dd)) * T_SEQ + tt]
                    = *(const bf16x4*)p4;
            }
        }
    }
}

// ---------------------------------------------------------------------------
// MFMA flash attention v6: R9 skeleton, NO K/V LDS staging, NO barriers.
// Block = 4 independent waves; wave owns 32 q-rows of a 128-row strip.
// K/V MFMA fragments read DIRECTLY from global (16B/lane; K tile 8KB and
// V tile 8KB are L1-resident after first touch, per-bh K/V 512KB L2-fits
// — m169 precedent: staging L2-fit data is pure overhead).
// Ps stays per-wave in LDS (same-wave DS ordering, no barrier needed).
// Waves 0/1 run 2qt+1 tiles, waves 2/3 run 2qt+2 (no dead masked tile).
// Balanced qt LUT as R9.  Defer-max (log2 units) + exp2; lane-partial lrow.
// ---------------------------------------------------------------------------
__global__ __launch_bounds__(256) void attn_mfma(
    const __bf16* __restrict__ qkb, const __bf16* __restrict__ vT,
    __bf16* __restrict__ aout)
{
    const int idx  = blockIdx.x;            // 0..1023
    const int slot = idx >> 6;
    const int j    = slot & 3, p = slot >> 2;
    const int qt   = (p == 0) ? 15 - j : (p == 1) ? 8 + j : (p == 2) ? 4 + j : 3 - j;
    const int bh   = idx & 63;
    const int b    = bh >> 4;
    const int h    = bh & 15;
    const int tid  = threadIdx.x;
    const int wid  = tid >> 6;
    const int lane = tid & 63;
    const int g    = lane >> 4;
    const int n    = lane & 15;

    const int q0    = qt * 128;
    const int qbase = q0 + wid * 32;
    const int nktw  = 2 * qt + 1 + (wid >> 1);   // per-wave tile count

    __shared__ __align__(16) char Ps[4][32 * 128];     // per-wave [q][kv]

    // ---- Q fragments: scale 1/8 * log2(e) folded in ----
    const float qscale = 0.125f * 1.44269504089f;
    bf16x8 qa[2][2];
    #pragma unroll
    for (int rb = 0; rb < 2; ++rb) {
        const size_t qrow = (size_t)(b * T_SEQ + qbase + rb * 16 + n) * 2048
                            + (size_t)h * HD;
        qa[rb][0] = *(const bf16x8*)&qkb[qrow + g * 8];
        qa[rb][1] = *(const bf16x8*)&qkb[qrow + 32 + g * 8];
        #pragma unroll
        for (int jj = 0; jj < 8; ++jj) {
            qa[rb][0][jj] = (__bf16)((float)qa[rb][0][jj] * qscale);
            qa[rb][1][jj] = (__bf16)((float)qa[rb][1][jj] * qscale);
        }
    }

    f32x4 o[2][4] = {};
    float mrow[2][4] = {};                  // defer-max base m=0 (log2 units)
    float lrow[2][4] = {};                  // lane-partial row sums

    // per-lane global bases for K and V fragment reads
    const __bf16* kbase = qkb + (size_t)b * T_SEQ * 2048 + 1024 + (size_t)h * HD
                          + g * 8;                         // + kv*2048 + cc*32
    const __bf16* vbase = vT + ((size_t)((b * NH + h) * HD + n)) * T_SEQ
                          + g * 8;                         // + nt*16*T + kb0 + cc*32

    for (int kt = 0; kt < nktw; ++kt) {
        const int kb0 = kt * 64;

        // ---- K fragments direct from global (L1/L2-hit after first touch) ----
        bf16x8 kf[2][4];
        #pragma unroll
        for (int cc = 0; cc < 2; ++cc)
            #pragma unroll
            for (int sub = 0; sub < 4; ++sub)
                kf[cc][sub] = *(const bf16x8*)(kbase
                    + (size_t)(kb0 + sub * 16 + n) * 2048 + cc * 32);

        // ---- S = Q K^T (log2 units) ----
        f32x4 s4[2][4] = {};
        __builtin_amdgcn_s_setprio(1);
        #pragma unroll
        for (int cc = 0; cc < 2; ++cc)
            #pragma unroll
            for (int rb = 0; rb < 2; ++rb)
                #pragma unroll
                for (int sub = 0; sub < 4; ++sub)
                    s4[rb][sub] = __builtin_amdgcn_mfma_f32_16x16x32_bf16(
                        qa[rb][cc], kf[cc][sub], s4[rb][sub], 0, 0, 0);
        __builtin_amdgcn_s_setprio(0);

        // ---- V fragments: issue now, consumed after softmax ----
        bf16x8 vf[2][4];
        #pragma unroll
        for (int cc = 0; cc < 2; ++cc)
            #pragma unroll
            for (int nt = 0; nt < 4; ++nt)
                vf[cc][nt] = *(const bf16x8*)(vbase
                    + (size_t)(nt * 16) * T_SEQ + kb0 + cc * 32);

        const bool needmask = (kb0 + 63 > qbase);   // wave-uniform

        #pragma unroll
        for (int rb = 0; rb < 2; ++rb) {
            if (needmask) {
                #pragma unroll
                for (int r = 0; r < 4; ++r) {
                    const int qrow = qbase + rb * 16 + 4 * g + r;
                    #pragma unroll
                    for (int sub = 0; sub < 4; ++sub)
                        if (kb0 + sub * 16 + n > qrow) s4[rb][sub][r] = -INFINITY;
                }
            }
            float pm[4];
            int ok = 1;
            #pragma unroll
            for (int r = 0; r < 4; ++r) {
                pm[r] = fmaxf(fmaxf(s4[rb][0][r], s4[rb][1][r]),
                              fmaxf(s4[rb][2][r], s4[rb][3][r]));
                ok &= (pm[r] <= mrow[rb][r] + 8.f);
            }
            if (__all(ok)) {
                // fast path: no max-reduce, no rescale, lane-partial sum
                #pragma unroll
                for (int r = 0; r < 4; ++r) {
                    const float m = mrow[rb][r];
                    const float p0 = exp2v(s4[rb][0][r] - m);
                    const float p1 = exp2v(s4[rb][1][r] - m);
                    const float p2 = exp2v(s4[rb][2][r] - m);
                    const float p3 = exp2v(s4[rb][3][r] - m);
                    lrow[rb][r] += (p0 + p1) + (p2 + p3);
                    char* prow = Ps[wid] + (rb * 16 + 4 * g + r) * 128;
                    const int pswz = ((4 * g + r) & 7) << 4;
                    *(__bf16*)(prow + ((2 * n)      ^ pswz)) = (__bf16)p0;
                    *(__bf16*)(prow + ((2 * n + 32) ^ pswz)) = (__bf16)p1;
                    *(__bf16*)(prow + ((2 * n + 64) ^ pswz)) = (__bf16)p2;
                    *(__bf16*)(prow + ((2 * n + 96) ^ pswz)) = (__bf16)p3;
                }
            } else {
                // slow path: butterfly max, rescale o and partial lrow
                #pragma unroll
                for (int r = 0; r < 4; ++r) {
                    float tm = pm[r];
                    #pragma unroll
                    for (int off = 1; off < 16; off <<= 1)
                        tm = fmaxf(tm, __shfl_xor(tm, off));
                    const float mnew = fmaxf(mrow[rb][r], tm);
                    const float corr = exp2v(mrow[rb][r] - mnew);
                    mrow[rb][r] = mnew;
                    const float p0 = exp2v(s4[rb][0][r] - mnew);
                    const float p1 = exp2v(s4[rb][1][r] - mnew);
                    const float p2 = exp2v(s4[rb][2][r] - mnew);
                    const float p3 = exp2v(s4[rb][3][r] - mnew);
                    lrow[rb][r] = lrow[rb][r] * corr + (p0 + p1) + (p2 + p3);
                    #pragma unroll
                    for (int nt = 0; nt < 4; ++nt) o[rb][nt][r] *= corr;
                    char* prow = Ps[wid] + (rb * 16 + 4 * g + r) * 128;
                    const int pswz = ((4 * g + r) & 7) << 4;
                    *(__bf16*)(prow + ((2 * n)      ^ pswz)) = (__bf16)p0;
                    *(__bf16*)(prow + ((2 * n + 32) ^ pswz)) = (__bf16)p1;
                    *(__bf16*)(prow + ((2 * n + 64) ^ pswz)) = (__bf16)p2;
                    *(__bf16*)(prow + ((2 * n + 96) ^ pswz)) = (__bf16)p3;
                }
            }
        }

        // ---- O += P V (P from per-wave LDS, V from regs) ----
        const int swzn = (n & 7) << 4;
        __builtin_amdgcn_s_setprio(1);
        #pragma unroll
        for (int cc = 0; cc < 2; ++cc) {
            #pragma unroll
            for (int rb = 0; rb < 2; ++rb) {
                bf16x8 pa = *(const bf16x8*)(Ps[wid] + (rb * 16 + n) * 128
                                             + ((cc * 64 + g * 16) ^ swzn));
                #pragma unroll
                for (int nt = 0; nt < 4; ++nt)
                    o[rb][nt] = __builtin_amdgcn_mfma_f32_16x16x32_bf16(
                        pa, vf[cc][nt], o[rb][nt], 0, 0, 0);
            }
        }
        __builtin_amdgcn_s_setprio(0);
    }

    // ---- final 16-lane reduce of lrow, normalize, store ----
    #pragma unroll
    for (int rb = 0; rb < 2; ++rb) {
        float inv[4];
        #pragma unroll
        for (int r = 0; r < 4; ++r) {
            float ssum = lrow[rb][r];
            #pragma unroll
            for (int off = 1; off < 16; off <<= 1)
                ssum += __shfl_xor(ssum, off);
            inv[r] = 1.f / ssum;
        }
        const size_t obase = (size_t)(b * T_SEQ + qbase + rb * 16) * D_MODEL
                             + (size_t)h * HD;
        #pragma unroll
        for (int nt = 0; nt < 4; ++nt)
            #pragma unroll
            for (int r = 0; r < 4; ++r)
                aout[obase + (size_t)(4 * g + r) * D_MODEL + nt * 16 + n]
                    = (__bf16)(o[rb][nt][r] * inv[r]);
    }
}

// ---------------------------------------------------------------------------
extern "C" void kernel_launch(void* const* d_in, const int* in_sizes, int n_in,
                              void* d_out, int out_size, void* d_ws, size_t ws_size,
                              hipStream_t stream)
{
    const float* x      = (const float*)d_in[0];
    const float* w_qkv  = (const float*)d_in[1];
    const float* b_qkv  = (const float*)d_in[2];
    const float* w_proj = (const float*)d_in[3];
    const float* b_proj = (const float*)d_in[4];
    float* out = (float*)d_out;

    char* ws = (char*)d_ws;
    __bf16* qkb    = (__bf16*)ws;                                   // 8192 x 2048
    __bf16* vTb    = qkb + (size_t)M_ROWS * 2048;                   // 64 x 64 x 2048
    __bf16* xb     = vTb + (size_t)NH * B_SZ * HD * T_SEQ;          // 8192 x 1024
    __bf16* wqkvT  = xb + (size_t)M_ROWS * D_MODEL;                 // 3072 x 1024
    __bf16* wprojT = wqkvT + (size_t)N_QKV * D_MODEL;               // 1024 x 1024
    __bf16* aout   = wprojT + (size_t)D_MODEL * D_MODEL;            // 8192 x 1024

    cvt_bf16<<<dim3(M_ROWS * D_MODEL / 8 / 256), 256, 0, stream>>>(
        x, xb, M_ROWS * D_MODEL / 8);
    transpose_cvt<<<dim3(N_QKV / 32, D_MODEL / 32), 256, 0, stream>>>(
        w_qkv, wqkvT, D_MODEL, N_QKV);
    transpose_cvt<<<dim3(D_MODEL / 32, D_MODEL / 32), 256, 0, stream>>>(
        w_proj, wprojT, D_MODEL, D_MODEL);

    gemm_mfma<1><<<dim3((M_ROWS / 128) * (N_QKV / 128)), 256, 0, stream>>>(
        xb, wqkvT, b_qkv, qkb, vTb, M_ROWS, N_QKV, D_MODEL);

    attn_mfma<<<dim3(B_SZ * NH * 16), 256, 0, stream>>>(qkb, vTb, aout);

    gemm_mfma<0><<<dim3((M_ROWS / 128) * (D_MODEL / 128)), 256, 0, stream>>>(
        aout, wprojT, b_proj, out, nullptr, M_ROWS, D_MODEL, D_MODEL);
}

// Round 12
// 224.890 us; speedup vs baseline: 1.0786x; 1.0786x over previous
//
#include <hip/hip_runtime.h>
#include <hip/hip_bf16.h>
#include <math.h>

#define D_MODEL 1024
#define NH      16
#define HD      64
#define T_SEQ   2048
#define B_SZ    4
#define M_ROWS  (B_SZ * T_SEQ)       // 8192
#define N_QKV   (3 * D_MODEL)        // 3072

typedef __bf16 bf16x8 __attribute__((ext_vector_type(8)));
typedef __bf16 bf16x4 __attribute__((ext_vector_type(4)));
typedef float  f32x4  __attribute__((ext_vector_type(4)));

__device__ __forceinline__ bf16x8 cvt8(float4 a, float4 b) {
    bf16x8 v;
    v[0]=(__bf16)a.x; v[1]=(__bf16)a.y; v[2]=(__bf16)a.z; v[3]=(__bf16)a.w;
    v[4]=(__bf16)b.x; v[5]=(__bf16)b.y; v[6]=(__bf16)b.z; v[7]=(__bf16)b.w;
    return v;
}

__device__ __forceinline__ void gload_lds16(const __bf16* g, __bf16* l) {
    __builtin_amdgcn_global_load_lds(
        (const __attribute__((address_space(1))) void*)g,
        (__attribute__((address_space(3))) void*)l, 16, 0, 0);
}

// raw v_exp_f32: computes 2^x (input already in log2 units)
__device__ __forceinline__ float exp2v(float x) {
    float r;
    asm("v_exp_f32 %0, %1" : "=v"(r) : "v"(x));
    return r;
}

// ---------------------------------------------------------------------------
// fp32 -> bf16 elementwise convert
// ---------------------------------------------------------------------------
__global__ __launch_bounds__(256) void cvt_bf16(const float* __restrict__ in,
                                                __bf16* __restrict__ out, int n8)
{
    int i = blockIdx.x * 256 + threadIdx.x;
    if (i < n8) {
        float4 a = ((const float4*)in)[2 * i];
        float4 b = ((const float4*)in)[2 * i + 1];
        ((bf16x8*)out)[i] = cvt8(a, b);
    }
}

// ---------------------------------------------------------------------------
// Transpose + convert: W[R][C] fp32 -> WT[C][R] bf16
// ---------------------------------------------------------------------------
__global__ __launch_bounds__(256) void transpose_cvt(
    const float* __restrict__ W, __bf16* __restrict__ WT, int R, int C)
{
    __shared__ float t[32][33];
    const int tr0 = blockIdx.y * 32, tc0 = blockIdx.x * 32;
    const int lr = threadIdx.x >> 5, lc = threadIdx.x & 31;
    #pragma unroll
    for (int i = 0; i < 4; ++i)
        t[lr + i * 8][lc] = W[(size_t)(tr0 + lr + i * 8) * C + tc0 + lc];
    __syncthreads();
    #pragma unroll
    for (int i = 0; i < 4; ++i)
        WT[(size_t)(tc0 + lr + i * 8) * R + tr0 + lc] = (__bf16)t[lc][lr + i * 8];
}

// ---------------------------------------------------------------------------
// bf16 MFMA GEMM (unchanged): 128x128 tile, BK=64, both-sides XOR swizzle.
// ---------------------------------------------------------------------------
template<int MODE>
__global__ __launch_bounds__(256) void gemm_mfma(
    const __bf16* __restrict__ A, const __bf16* __restrict__ BT,
    const float* __restrict__ bias, void* __restrict__ C0,
    __bf16* __restrict__ vT, int M, int N, int K)
{
    __shared__ __bf16 As[128 * 64];
    __shared__ __bf16 Bs[128 * 64];

    const int nbn = N >> 7;
    const int nwg = gridDim.x;
    int bid = blockIdx.x;
    bid = (bid & 7) * (nwg >> 3) + (bid >> 3);       // XCD swizzle (nwg % 8 == 0)
    const int tm = bid / nbn, tn = bid % nbn;
    const int row0 = tm << 7, col0 = tn << 7;

    const int tid  = threadIdx.x;
    const int wid  = tid >> 6, lane = tid & 63;
    const int wm   = wid >> 1, wn = wid & 1;
    const int g    = lane >> 4, r16 = lane & 15;

    f32x4 acc[4][4] = {};

    for (int k0 = 0; k0 < K; k0 += 64) {
        #pragma unroll
        for (int i = 0; i < 4; ++i) {
            const int seg = wid * 4 + i;                 // 0..15
            const int row = seg * 8 + (lane >> 3);       // 0..127
            const int kel = ((lane & 7) * 8) ^ ((row & 7) * 8);
            gload_lds16(A  + (size_t)(row0 + row) * K + k0 + kel, As + seg * 512);
            gload_lds16(BT + (size_t)(col0 + row) * K + k0 + kel, Bs + seg * 512);
        }
        __syncthreads();

        #pragma unroll
        for (int kk = 0; kk < 2; ++kk) {
            bf16x8 af[4], bfr[4];
            #pragma unroll
            for (int mt = 0; mt < 4; ++mt) {
                const int row = wm * 64 + mt * 16 + r16;
                af[mt] = *(const bf16x8*)((const char*)As + row * 128
                             + ((kk * 64 + g * 16) ^ ((row & 7) << 4)));
            }
            #pragma unroll
            for (int nt = 0; nt < 4; ++nt) {
                const int row = wn * 64 + nt * 16 + r16;
                bfr[nt] = *(const bf16x8*)((const char*)Bs + row * 128
                             + ((kk * 64 + g * 16) ^ ((row & 7) << 4)));
            }
            #pragma unroll
            for (int mt = 0; mt < 4; ++mt)
                #pragma unroll
                for (int nt = 0; nt < 4; ++nt)
                    acc[mt][nt] = __builtin_amdgcn_mfma_f32_16x16x32_bf16(
                        af[mt], bfr[nt], acc[mt][nt], 0, 0, 0);
        }
        __syncthreads();
    }

    const bool isV = (MODE == 1) && (tn >= 16);

    #pragma unroll
    for (int mt = 0; mt < 4; ++mt) {
        #pragma unroll
        for (int nt = 0; nt < 4; ++nt) {
            const int col = col0 + wn * 64 + nt * 16 + r16;
            const float bv = bias[col];
            const int rowb = row0 + wm * 64 + mt * 16 + g * 4;
            if (MODE == 0) {
                #pragma unroll
                for (int j = 0; j < 4; ++j)
                    ((float*)C0)[(size_t)(rowb + j) * N + col] = acc[mt][nt][j] + bv;
            } else if (!isV) {
                #pragma unroll
                for (int j = 0; j < 4; ++j)
                    ((__bf16*)C0)[(size_t)(rowb + j) * 2048 + col] =
                        (__bf16)(acc[mt][nt][j] + bv);
            } else {
                const int hh = (col - 2048) >> 6, dd = (col - 2048) & 63;
                const int bb = rowb >> 11, tt = rowb & 2047;
                __bf16 p4[4];
                #pragma unroll
                for (int j = 0; j < 4; ++j) p4[j] = (__bf16)(acc[mt][nt][j] + bv);
                *(bf16x4*)&vT[((size_t)((bb * NH + hh) * HD + dd)) * T_SEQ + tt]
                    = *(const bf16x4*)p4;
            }
        }
    }
}

// ---------------------------------------------------------------------------
// MFMA flash attention v7: R9 strip geometry, 2-wave blocks, wave owns 64
// q-rows (rb=4).  Per-block staging identical to R9 (K/V once per tile per
// 128 q-rows) but per-wave fixed costs amortize over 2x the MFMA; lockstep
// width 2 waves; staging uses R10's 128-thread pattern (0 bank conflicts).
// Softmax inlined per-rb to bound s4 liveness.  Grid 1024, balanced qt LUT
// ({15,8,4,3},{14,9,5,2},... each CU slot-group sums 68 tiles).
// Defer-max (log2 units) + exp2; lane-partial lrow; LDS 32KB.
// ---------------------------------------------------------------------------
__global__ __launch_bounds__(128) void attn_mfma(
    const __bf16* __restrict__ qkb, const __bf16* __restrict__ vT,
    __bf16* __restrict__ aout)
{
    const int idx  = blockIdx.x;            // 0..1023
    const int slot = idx >> 6;
    const int j    = slot & 3, p = slot >> 2;
    const int qt   = (p == 0) ? 15 - j : (p == 1) ? 8 + j : (p == 2) ? 4 + j : 3 - j;
    const int bh   = idx & 63;
    const int b    = bh >> 4;
    const int h    = bh & 15;
    const int tid  = threadIdx.x;
    const int wid  = tid >> 6;              // 0..1
    const int lane = tid & 63;
    const int g    = lane >> 4;
    const int n    = lane & 15;
    const int swzn = (n & 7) << 4;

    const int q0    = qt * 128;
    const int qbase = q0 + wid * 64;        // wave owns 64 q-rows
    const int nkt   = 2 * qt + 2;

    __shared__ __align__(16) char Ks[64 * 128];        // [kv][d]
    __shared__ __align__(16) char Vs[64 * 128];        // [d][kv]
    __shared__ __align__(16) char Ps[2][64 * 128];     // per-wave [q][kv]

    // staging (R10 pattern, 0-conflict): thread owns 64B of one K row + one V row
    const int srow = tid >> 1;              // 0..63
    const int sch2 = tid & 1;               // half selector
    const int swzw = (srow & 7) << 4;

    // ---- Q fragments: scale 1/8 * log2(e) folded in ----
    const float qscale = 0.125f * 1.44269504089f;
    bf16x8 qa[4][2];
    #pragma unroll
    for (int rb = 0; rb < 4; ++rb) {
        const size_t qrow = (size_t)(b * T_SEQ + qbase + rb * 16 + n) * 2048
                            + (size_t)h * HD;
        qa[rb][0] = *(const bf16x8*)&qkb[qrow + g * 8];
        qa[rb][1] = *(const bf16x8*)&qkb[qrow + 32 + g * 8];
        #pragma unroll
        for (int jj = 0; jj < 8; ++jj) {
            qa[rb][0][jj] = (__bf16)((float)qa[rb][0][jj] * qscale);
            qa[rb][1][jj] = (__bf16)((float)qa[rb][1][jj] * qscale);
        }
    }

    f32x4 o[4][4] = {};
    float mrow[4][4] = {};                  // defer-max base m=0 (log2 units)
    float lrow[4][4] = {};                  // lane-partial row sums

    const __bf16* gK = qkb + (size_t)(b * T_SEQ + srow) * 2048 + 1024
                       + (size_t)h * HD + sch2 * 32;
    const __bf16* gV = vT + ((size_t)((b * NH + h) * HD + srow)) * T_SEQ + sch2 * 32;

    bf16x8 kreg[4], vreg[4];
    #pragma unroll
    for (int c = 0; c < 4; ++c) {
        kreg[c] = *(const bf16x8*)(gK + c * 8);
        vreg[c] = *(const bf16x8*)(gV + c * 8);
    }

    for (int kt = 0; kt < nkt; ++kt) {
        #pragma unroll
        for (int c = 0; c < 4; ++c) {
            const int boff = (sch2 * 64 + c * 16) ^ swzw;
            *(bf16x8*)(Ks + srow * 128 + boff) = kreg[c];
            *(bf16x8*)(Vs + srow * 128 + boff) = vreg[c];
        }
        __syncthreads();

        if (kt + 1 < nkt) {
            const size_t kb2 = (size_t)(kt + 1) * 64;
            #pragma unroll
            for (int c = 0; c < 4; ++c) {
                kreg[c] = *(const bf16x8*)(gK + kb2 * 2048 + c * 8);
                vreg[c] = *(const bf16x8*)(gV + kb2 + c * 8);
            }
        }

        const int kb0 = kt * 64;
        const bool active = (kb0 <= qbase + 63);    // wave-uniform

        if (active) {
            // ---- K fragments (shared across rb) ----
            bf16x8 kf[2][4];
            #pragma unroll
            for (int cc = 0; cc < 2; ++cc)
                #pragma unroll
                for (int sub = 0; sub < 4; ++sub)
                    kf[cc][sub] = *(const bf16x8*)(Ks + (sub * 16 + n) * 128
                                                   + ((cc * 64 + g * 16) ^ swzn));

            const bool needmask = (kb0 + 63 > qbase);   // wave-uniform

            // ---- per-rb: QK MFMA then softmax (bounds s4 liveness) ----
            #pragma unroll
            for (int rb = 0; rb < 4; ++rb) {
                f32x4 s4[4] = {};
                __builtin_amdgcn_s_setprio(1);
                #pragma unroll
                for (int cc = 0; cc < 2; ++cc)
                    #pragma unroll
                    for (int sub = 0; sub < 4; ++sub)
                        s4[sub] = __builtin_amdgcn_mfma_f32_16x16x32_bf16(
                            qa[rb][cc], kf[cc][sub], s4[sub], 0, 0, 0);
                __builtin_amdgcn_s_setprio(0);

                if (needmask) {
                    #pragma unroll
                    for (int r = 0; r < 4; ++r) {
                        const int qrow = qbase + rb * 16 + 4 * g + r;
                        #pragma unroll
                        for (int sub = 0; sub < 4; ++sub)
                            if (kb0 + sub * 16 + n > qrow) s4[sub][r] = -INFINITY;
                    }
                }
                float pm[4];
                int ok = 1;
                #pragma unroll
                for (int r = 0; r < 4; ++r) {
                    pm[r] = fmaxf(fmaxf(s4[0][r], s4[1][r]),
                                  fmaxf(s4[2][r], s4[3][r]));
                    ok &= (pm[r] <= mrow[rb][r] + 8.f);
                }
                if (__all(ok)) {
                    // fast path: no max-reduce, no rescale, lane-partial sum
                    #pragma unroll
                    for (int r = 0; r < 4; ++r) {
                        const float m = mrow[rb][r];
                        const float p0 = exp2v(s4[0][r] - m);
                        const float p1 = exp2v(s4[1][r] - m);
                        const float p2 = exp2v(s4[2][r] - m);
                        const float p3 = exp2v(s4[3][r] - m);
                        lrow[rb][r] += (p0 + p1) + (p2 + p3);
                        char* prow = Ps[wid] + (rb * 16 + 4 * g + r) * 128;
                        const int pswz = ((4 * g + r) & 7) << 4;
                        *(__bf16*)(prow + ((2 * n)      ^ pswz)) = (__bf16)p0;
                        *(__bf16*)(prow + ((2 * n + 32) ^ pswz)) = (__bf16)p1;
                        *(__bf16*)(prow + ((2 * n + 64) ^ pswz)) = (__bf16)p2;
                        *(__bf16*)(prow + ((2 * n + 96) ^ pswz)) = (__bf16)p3;
                    }
                } else {
                    // slow path: butterfly max, rescale o and partial lrow
                    #pragma unroll
                    for (int r = 0; r < 4; ++r) {
                        float tm = pm[r];
                        #pragma unroll
                        for (int off = 1; off < 16; off <<= 1)
                            tm = fmaxf(tm, __shfl_xor(tm, off));
                        const float mnew = fmaxf(mrow[rb][r], tm);
                        const float corr = exp2v(mrow[rb][r] - mnew);
                        mrow[rb][r] = mnew;
                        const float p0 = exp2v(s4[0][r] - mnew);
                        const float p1 = exp2v(s4[1][r] - mnew);
                        const float p2 = exp2v(s4[2][r] - mnew);
                        const float p3 = exp2v(s4[3][r] - mnew);
                        lrow[rb][r] = lrow[rb][r] * corr + (p0 + p1) + (p2 + p3);
                        #pragma unroll
                        for (int nt = 0; nt < 4; ++nt) o[rb][nt][r] *= corr;
                        char* prow = Ps[wid] + (rb * 16 + 4 * g + r) * 128;
                        const int pswz = ((4 * g + r) & 7) << 4;
                        *(__bf16*)(prow + ((2 * n)      ^ pswz)) = (__bf16)p0;
                        *(__bf16*)(prow + ((2 * n + 32) ^ pswz)) = (__bf16)p1;
                        *(__bf16*)(prow + ((2 * n + 64) ^ pswz)) = (__bf16)p2;
                        *(__bf16*)(prow + ((2 * n + 96) ^ pswz)) = (__bf16)p3;
                    }
                }
            }

            // ---- O += P V ----
            __builtin_amdgcn_s_setprio(1);
            #pragma unroll
            for (int cc = 0; cc < 2; ++cc) {
                bf16x8 vf[4];
                #pragma unroll
                for (int nt = 0; nt < 4; ++nt)
                    vf[nt] = *(const bf16x8*)(Vs + (nt * 16 + n) * 128
                                              + ((cc * 64 + g * 16) ^ swzn));
                #pragma unroll
                for (int rb = 0; rb < 4; ++rb) {
                    bf16x8 pa = *(const bf16x8*)(Ps[wid] + (rb * 16 + n) * 128
                                                 + ((cc * 64 + g * 16) ^ swzn));
                    #pragma unroll
                    for (int nt = 0; nt < 4; ++nt)
                        o[rb][nt] = __builtin_amdgcn_mfma_f32_16x16x32_bf16(
                            pa, vf[nt], o[rb][nt], 0, 0, 0);
                }
            }
            __builtin_amdgcn_s_setprio(0);
        }
        __syncthreads();
    }

    // ---- final 16-lane reduce of lrow, normalize, store ----
    #pragma unroll
    for (int rb = 0; rb < 4; ++rb) {
        float inv[4];
        #pragma unroll
        for (int r = 0; r < 4; ++r) {
            float ssum = lrow[rb][r];
            #pragma unroll
            for (int off = 1; off < 16; off <<= 1)
                ssum += __shfl_xor(ssum, off);
            inv[r] = 1.f / ssum;
        }
        const size_t obase = (size_t)(b * T_SEQ + qbase + rb * 16) * D_MODEL
                             + (size_t)h * HD;
        #pragma unroll
        for (int nt = 0; nt < 4; ++nt)
            #pragma unroll
            for (int r = 0; r < 4; ++r)
                aout[obase + (size_t)(4 * g + r) * D_MODEL + nt * 16 + n]
                    = (__bf16)(o[rb][nt][r] * inv[r]);
    }
}

// ---------------------------------------------------------------------------
extern "C" void kernel_launch(void* const* d_in, const int* in_sizes, int n_in,
                              void* d_out, int out_size, void* d_ws, size_t ws_size,
                              hipStream_t stream)
{
    const float* x      = (const float*)d_in[0];
    const float* w_qkv  = (const float*)d_in[1];
    const float* b_qkv  = (const float*)d_in[2];
    const float* w_proj = (const float*)d_in[3];
    const float* b_proj = (const float*)d_in[4];
    float* out = (float*)d_out;

    char* ws = (char*)d_ws;
    __bf16* qkb    = (__bf16*)ws;                                   // 8192 x 2048
    __bf16* vTb    = qkb + (size_t)M_ROWS * 2048;                   // 64 x 64 x 2048
    __bf16* xb     = vTb + (size_t)NH * B_SZ * HD * T_SEQ;          // 8192 x 1024
    __bf16* wqkvT  = xb + (size_t)M_ROWS * D_MODEL;                 // 3072 x 1024
    __bf16* wprojT = wqkvT + (size_t)N_QKV * D_MODEL;               // 1024 x 1024
    __bf16* aout   = wprojT + (size_t)D_MODEL * D_MODEL;            // 8192 x 1024

    cvt_bf16<<<dim3(M_ROWS * D_MODEL / 8 / 256), 256, 0, stream>>>(
        x, xb, M_ROWS * D_MODEL / 8);
    transpose_cvt<<<dim3(N_QKV / 32, D_MODEL / 32), 256, 0, stream>>>(
        w_qkv, wqkvT, D_MODEL, N_QKV);
    transpose_cvt<<<dim3(D_MODEL / 32, D_MODEL / 32), 256, 0, stream>>>(
        w_proj, wprojT, D_MODEL, D_MODEL);

    gemm_mfma<1><<<dim3((M_ROWS / 128) * (N_QKV / 128)), 256, 0, stream>>>(
        xb, wqkvT, b_qkv, qkb, vTb, M_ROWS, N_QKV, D_MODEL);

    attn_mfma<<<dim3(B_SZ * NH * 16), 128, 0, stream>>>(qkb, vTb, aout);

    gemm_mfma<0><<<dim3((M_ROWS / 128) * (D_MODEL / 128)), 256, 0, stream>>>(
        aout, wprojT, b_proj, out, nullptr, M_ROWS, D_MODEL, D_MODEL);
}

// Round 13
// 194.727 us; speedup vs baseline: 1.2457x; 1.1549x over previous
//
#include <hip/hip_runtime.h>
#include <hip/hip_bf16.h>
#include <math.h>

#define D_MODEL 1024
#define NH      16
#define HD      64
#define T_SEQ   2048
#define B_SZ    4
#define M_ROWS  (B_SZ * T_SEQ)       // 8192
#define N_QKV   (3 * D_MODEL)        // 3072

typedef __bf16 bf16x8 __attribute__((ext_vector_type(8)));
typedef __bf16 bf16x4 __attribute__((ext_vector_type(4)));
typedef float  f32x4  __attribute__((ext_vector_type(4)));

__device__ __forceinline__ bf16x8 cvt8(float4 a, float4 b) {
    bf16x8 v;
    v[0]=(__bf16)a.x; v[1]=(__bf16)a.y; v[2]=(__bf16)a.z; v[3]=(__bf16)a.w;
    v[4]=(__bf16)b.x; v[5]=(__bf16)b.y; v[6]=(__bf16)b.z; v[7]=(__bf16)b.w;
    return v;
}

__device__ __forceinline__ void gload_lds16(const __bf16* g, __bf16* l) {
    __builtin_amdgcn_global_load_lds(
        (const __attribute__((address_space(1))) void*)g,
        (__attribute__((address_space(3))) void*)l, 16, 0, 0);
}

// raw v_exp_f32: computes 2^x (input already in log2 units)
__device__ __forceinline__ float exp2v(float x) {
    float r;
    asm("v_exp_f32 %0, %1" : "=v"(r) : "v"(x));
    return r;
}

// ---------------------------------------------------------------------------
// fp32 -> bf16 elementwise convert
// ---------------------------------------------------------------------------
__global__ __launch_bounds__(256) void cvt_bf16(const float* __restrict__ in,
                                                __bf16* __restrict__ out, int n8)
{
    int i = blockIdx.x * 256 + threadIdx.x;
    if (i < n8) {
        float4 a = ((const float4*)in)[2 * i];
        float4 b = ((const float4*)in)[2 * i + 1];
        ((bf16x8*)out)[i] = cvt8(a, b);
    }
}

// ---------------------------------------------------------------------------
// Transpose + convert: W[R][C] fp32 -> WT[C][R] bf16
// ---------------------------------------------------------------------------
__global__ __launch_bounds__(256) void transpose_cvt(
    const float* __restrict__ W, __bf16* __restrict__ WT, int R, int C)
{
    __shared__ float t[32][33];
    const int tr0 = blockIdx.y * 32, tc0 = blockIdx.x * 32;
    const int lr = threadIdx.x >> 5, lc = threadIdx.x & 31;
    #pragma unroll
    for (int i = 0; i < 4; ++i)
        t[lr + i * 8][lc] = W[(size_t)(tr0 + lr + i * 8) * C + tc0 + lc];
    __syncthreads();
    #pragma unroll
    for (int i = 0; i < 4; ++i)
        WT[(size_t)(tc0 + lr + i * 8) * R + tr0 + lc] = (__bf16)t[lc][lr + i * 8];
}

// ---------------------------------------------------------------------------
// bf16 MFMA GEMM (unchanged): 128x128 tile, BK=64, both-sides XOR swizzle.
// ---------------------------------------------------------------------------
template<int MODE>
__global__ __launch_bounds__(256) void gemm_mfma(
    const __bf16* __restrict__ A, const __bf16* __restrict__ BT,
    const float* __restrict__ bias, void* __restrict__ C0,
    __bf16* __restrict__ vT, int M, int N, int K)
{
    __shared__ __bf16 As[128 * 64];
    __shared__ __bf16 Bs[128 * 64];

    const int nbn = N >> 7;
    const int nwg = gridDim.x;
    int bid = blockIdx.x;
    bid = (bid & 7) * (nwg >> 3) + (bid >> 3);       // XCD swizzle (nwg % 8 == 0)
    const int tm = bid / nbn, tn = bid % nbn;
    const int row0 = tm << 7, col0 = tn << 7;

    const int tid  = threadIdx.x;
    const int wid  = tid >> 6, lane = tid & 63;
    const int wm   = wid >> 1, wn = wid & 1;
    const int g    = lane >> 4, r16 = lane & 15;

    f32x4 acc[4][4] = {};

    for (int k0 = 0; k0 < K; k0 += 64) {
        #pragma unroll
        for (int i = 0; i < 4; ++i) {
            const int seg = wid * 4 + i;                 // 0..15
            const int row = seg * 8 + (lane >> 3);       // 0..127
            const int kel = ((lane & 7) * 8) ^ ((row & 7) * 8);
            gload_lds16(A  + (size_t)(row0 + row) * K + k0 + kel, As + seg * 512);
            gload_lds16(BT + (size_t)(col0 + row) * K + k0 + kel, Bs + seg * 512);
        }
        __syncthreads();

        #pragma unroll
        for (int kk = 0; kk < 2; ++kk) {
            bf16x8 af[4], bfr[4];
            #pragma unroll
            for (int mt = 0; mt < 4; ++mt) {
                const int row = wm * 64 + mt * 16 + r16;
                af[mt] = *(const bf16x8*)((const char*)As + row * 128
                             + ((kk * 64 + g * 16) ^ ((row & 7) << 4)));
            }
            #pragma unroll
            for (int nt = 0; nt < 4; ++nt) {
                const int row = wn * 64 + nt * 16 + r16;
                bfr[nt] = *(const bf16x8*)((const char*)Bs + row * 128
                             + ((kk * 64 + g * 16) ^ ((row & 7) << 4)));
            }
            #pragma unroll
            for (int mt = 0; mt < 4; ++mt)
                #pragma unroll
                for (int nt = 0; nt < 4; ++nt)
                    acc[mt][nt] = __builtin_amdgcn_mfma_f32_16x16x32_bf16(
                        af[mt], bfr[nt], acc[mt][nt], 0, 0, 0);
        }
        __syncthreads();
    }

    const bool isV = (MODE == 1) && (tn >= 16);

    #pragma unroll
    for (int mt = 0; mt < 4; ++mt) {
        #pragma unroll
        for (int nt = 0; nt < 4; ++nt) {
            const int col = col0 + wn * 64 + nt * 16 + r16;
            const float bv = bias[col];
            const int rowb = row0 + wm * 64 + mt * 16 + g * 4;
            if (MODE == 0) {
                #pragma unroll
                for (int j = 0; j < 4; ++j)
                    ((float*)C0)[(size_t)(rowb + j) * N + col] = acc[mt][nt][j] + bv;
            } else if (!isV) {
                #pragma unroll
                for (int j = 0; j < 4; ++j)
                    ((__bf16*)C0)[(size_t)(rowb + j) * 2048 + col] =
                        (__bf16)(acc[mt][nt][j] + bv);
            } else {
                const int hh = (col - 2048) >> 6, dd = (col - 2048) & 63;
                const int bb = rowb >> 11, tt = rowb & 2047;
                __bf16 p4[4];
                #pragma unroll
                for (int j = 0; j < 4; ++j) p4[j] = (__bf16)(acc[mt][nt][j] + bv);
                *(bf16x4*)&vT[((size_t)((bb * NH + hh) * HD + dd)) * T_SEQ + tt]
                    = *(const bf16x4*)p4;
            }
        }
    }
}

// ---------------------------------------------------------------------------
// MFMA flash attention v3.3 = R9 (verified best, 92.6us) + 0-conflict staging.
// Block = 4 waves = one 128-row q-strip; wave owns 32 q-rows.  Grid 1024;
// balanced qt LUT ({15,8,4,3},{14,9,5,2},... each slot-group sums 68 tiles).
// ONLY waves 0/1 (tid<128) stage K/V, using the R10/R12-verified mapping
// (srow=tid>>1, 4x b128/thread) which measured 0 LDS bank conflicts, vs
// R9's 256-thread pattern which measured 2.2e6.  Everything else == R9.
// Defer-max (log2 units) + exp2; lane-partial lrow; masked-tile skip.
// ---------------------------------------------------------------------------
__global__ __launch_bounds__(256) void attn_mfma(
    const __bf16* __restrict__ qkb, const __bf16* __restrict__ vT,
    __bf16* __restrict__ aout)
{
    const int idx  = blockIdx.x;            // 0..1023
    const int slot = idx >> 6;
    const int j    = slot & 3, p = slot >> 2;
    const int qt   = (p == 0) ? 15 - j : (p == 1) ? 8 + j : (p == 2) ? 4 + j : 3 - j;
    const int bh   = idx & 63;
    const int b    = bh >> 4;
    const int h    = bh & 15;
    const int tid  = threadIdx.x;
    const int wid  = tid >> 6;
    const int lane = tid & 63;
    const int g    = lane >> 4;
    const int n    = lane & 15;
    const int swzn = (n & 7) << 4;

    const int q0    = qt * 128;
    const int qbase = q0 + wid * 32;
    const int nkt   = 2 * qt + 2;

    __shared__ __align__(16) char Ks[64 * 128];        // [kv][d]
    __shared__ __align__(16) char Vs[64 * 128];        // [d][kv]
    __shared__ __align__(16) char Ps[4][32 * 128];     // per-wave [q][kv]

    // staging (R10/R12 0-conflict pattern, waves 0/1 only):
    // thread owns 64B (4 x b128) of one K row and one V row
    const bool stager = (tid < 128);
    const int  srow   = (tid >> 1) & 63;    // 0..63
    const int  sch2   = tid & 1;            // half selector
    const int  swzw   = (srow & 7) << 4;

    // ---- Q fragments: scale 1/8 * log2(e) folded in ----
    const float qscale = 0.125f * 1.44269504089f;
    bf16x8 qa[2][2];
    #pragma unroll
    for (int rb = 0; rb < 2; ++rb) {
        const size_t qrow = (size_t)(b * T_SEQ + qbase + rb * 16 + n) * 2048
                            + (size_t)h * HD;
        qa[rb][0] = *(const bf16x8*)&qkb[qrow + g * 8];
        qa[rb][1] = *(const bf16x8*)&qkb[qrow + 32 + g * 8];
        #pragma unroll
        for (int jj = 0; jj < 8; ++jj) {
            qa[rb][0][jj] = (__bf16)((float)qa[rb][0][jj] * qscale);
            qa[rb][1][jj] = (__bf16)((float)qa[rb][1][jj] * qscale);
        }
    }

    f32x4 o[2][4] = {};
    float mrow[2][4] = {};                  // defer-max base m=0 (log2 units)
    float lrow[2][4] = {};                  // lane-partial row sums

    const __bf16* gK = qkb + (size_t)(b * T_SEQ + srow) * 2048 + 1024
                       + (size_t)h * HD + sch2 * 32;
    const __bf16* gV = vT + ((size_t)((b * NH + h) * HD + srow)) * T_SEQ + sch2 * 32;

    bf16x8 kreg[4] = {}, vreg[4] = {};
    if (stager) {
        #pragma unroll
        for (int c = 0; c < 4; ++c) {
            kreg[c] = *(const bf16x8*)(gK + c * 8);
            vreg[c] = *(const bf16x8*)(gV + c * 8);
        }
    }

    for (int kt = 0; kt < nkt; ++kt) {
        if (stager) {
            #pragma unroll
            for (int c = 0; c < 4; ++c) {
                const int boff = (sch2 * 64 + c * 16) ^ swzw;
                *(bf16x8*)(Ks + srow * 128 + boff) = kreg[c];
                *(bf16x8*)(Vs + srow * 128 + boff) = vreg[c];
            }
        }
        __syncthreads();

        if (stager && kt + 1 < nkt) {
            const size_t kb2 = (size_t)(kt + 1) * 64;
            #pragma unroll
            for (int c = 0; c < 4; ++c) {
                kreg[c] = *(const bf16x8*)(gK + kb2 * 2048 + c * 8);
                vreg[c] = *(const bf16x8*)(gV + kb2 + c * 8);
            }
        }

        const int kb0 = kt * 64;
        const bool active = (kb0 <= qbase + 31);    // wave-uniform: any unmasked kv?

        if (active) {
            // ---- S = Q K^T (log2 units) ----
            f32x4 s4[2][4] = {};
            __builtin_amdgcn_s_setprio(1);
            #pragma unroll
            for (int cc = 0; cc < 2; ++cc) {
                bf16x8 kf[4];
                #pragma unroll
                for (int sub = 0; sub < 4; ++sub)
                    kf[sub] = *(const bf16x8*)(Ks + (sub * 16 + n) * 128
                                               + ((cc * 64 + g * 16) ^ swzn));
                #pragma unroll
                for (int rb = 0; rb < 2; ++rb)
                    #pragma unroll
                    for (int sub = 0; sub < 4; ++sub)
                        s4[rb][sub] = __builtin_amdgcn_mfma_f32_16x16x32_bf16(
                            qa[rb][cc], kf[sub], s4[rb][sub], 0, 0, 0);
            }
            __builtin_amdgcn_s_setprio(0);

            const bool needmask = (kb0 + 63 > qbase);   // wave-uniform

            #pragma unroll
            for (int rb = 0; rb < 2; ++rb) {
                if (needmask) {
                    #pragma unroll
                    for (int r = 0; r < 4; ++r) {
                        const int qrow = qbase + rb * 16 + 4 * g + r;
                        #pragma unroll
                        for (int sub = 0; sub < 4; ++sub)
                            if (kb0 + sub * 16 + n > qrow) s4[rb][sub][r] = -INFINITY;
                    }
                }
                float pm[4];
                int ok = 1;
                #pragma unroll
                for (int r = 0; r < 4; ++r) {
                    pm[r] = fmaxf(fmaxf(s4[rb][0][r], s4[rb][1][r]),
                                  fmaxf(s4[rb][2][r], s4[rb][3][r]));
                    ok &= (pm[r] <= mrow[rb][r] + 8.f);
                }
                if (__all(ok)) {
                    // fast path: no max-reduce, no rescale, lane-partial sum
                    #pragma unroll
                    for (int r = 0; r < 4; ++r) {
                        const float m = mrow[rb][r];
                        const float p0 = exp2v(s4[rb][0][r] - m);
                        const float p1 = exp2v(s4[rb][1][r] - m);
                        const float p2 = exp2v(s4[rb][2][r] - m);
                        const float p3 = exp2v(s4[rb][3][r] - m);
                        lrow[rb][r] += (p0 + p1) + (p2 + p3);
                        char* prow = Ps[wid] + (rb * 16 + 4 * g + r) * 128;
                        const int pswz = ((4 * g + r) & 7) << 4;
                        *(__bf16*)(prow + ((2 * n)      ^ pswz)) = (__bf16)p0;
                        *(__bf16*)(prow + ((2 * n + 32) ^ pswz)) = (__bf16)p1;
                        *(__bf16*)(prow + ((2 * n + 64) ^ pswz)) = (__bf16)p2;
                        *(__bf16*)(prow + ((2 * n + 96) ^ pswz)) = (__bf16)p3;
                    }
                } else {
                    // slow path: butterfly max, rescale o and partial lrow
                    #pragma unroll
                    for (int r = 0; r < 4; ++r) {
                        float tm = pm[r];
                        #pragma unroll
                        for (int off = 1; off < 16; off <<= 1)
                            tm = fmaxf(tm, __shfl_xor(tm, off));
                        const float mnew = fmaxf(mrow[rb][r], tm);
                        const float corr = exp2v(mrow[rb][r] - mnew);
                        mrow[rb][r] = mnew;
                        const float p0 = exp2v(s4[rb][0][r] - mnew);
                        const float p1 = exp2v(s4[rb][1][r] - mnew);
                        const float p2 = exp2v(s4[rb][2][r] - mnew);
                        const float p3 = exp2v(s4[rb][3][r] - mnew);
                        lrow[rb][r] = lrow[rb][r] * corr + (p0 + p1) + (p2 + p3);
                        #pragma unroll
                        for (int nt = 0; nt < 4; ++nt) o[rb][nt][r] *= corr;
                        char* prow = Ps[wid] + (rb * 16 + 4 * g + r) * 128;
                        const int pswz = ((4 * g + r) & 7) << 4;
                        *(__bf16*)(prow + ((2 * n)      ^ pswz)) = (__bf16)p0;
                        *(__bf16*)(prow + ((2 * n + 32) ^ pswz)) = (__bf16)p1;
                        *(__bf16*)(prow + ((2 * n + 64) ^ pswz)) = (__bf16)p2;
                        *(__bf16*)(prow + ((2 * n + 96) ^ pswz)) = (__bf16)p3;
                    }
                }
            }

            // ---- O += P V ----
            __builtin_amdgcn_s_setprio(1);
            #pragma unroll
            for (int cc = 0; cc < 2; ++cc) {
                bf16x8 vf[4];
                #pragma unroll
                for (int nt = 0; nt < 4; ++nt)
                    vf[nt] = *(const bf16x8*)(Vs + (nt * 16 + n) * 128
                                              + ((cc * 64 + g * 16) ^ swzn));
                #pragma unroll
                for (int rb = 0; rb < 2; ++rb) {
                    bf16x8 pa = *(const bf16x8*)(Ps[wid] + (rb * 16 + n) * 128
                                                 + ((cc * 64 + g * 16) ^ swzn));
                    #pragma unroll
                    for (int nt = 0; nt < 4; ++nt)
                        o[rb][nt] = __builtin_amdgcn_mfma_f32_16x16x32_bf16(
                            pa, vf[nt], o[rb][nt], 0, 0, 0);
                }
            }
            __builtin_amdgcn_s_setprio(0);
        }
        __syncthreads();
    }

    // ---- final 16-lane reduce of lrow, normalize, store ----
    #pragma unroll
    for (int rb = 0; rb < 2; ++rb) {
        float inv[4];
        #pragma unroll
        for (int r = 0; r < 4; ++r) {
            float ssum = lrow[rb][r];
            #pragma unroll
            for (int off = 1; off < 16; off <<= 1)
                ssum += __shfl_xor(ssum, off);
            inv[r] = 1.f / ssum;
        }
        const size_t obase = (size_t)(b * T_SEQ + qbase + rb * 16) * D_MODEL
                             + (size_t)h * HD;
        #pragma unroll
        for (int nt = 0; nt < 4; ++nt)
            #pragma unroll
            for (int r = 0; r < 4; ++r)
                aout[obase + (size_t)(4 * g + r) * D_MODEL + nt * 16 + n]
                    = (__bf16)(o[rb][nt][r] * inv[r]);
    }
}

// ---------------------------------------------------------------------------
extern "C" void kernel_launch(void* const* d_in, const int* in_sizes, int n_in,
                              void* d_out, int out_size, void* d_ws, size_t ws_size,
                              hipStream_t stream)
{
    const float* x      = (const float*)d_in[0];
    const float* w_qkv  = (const float*)d_in[1];
    const float* b_qkv  = (const float*)d_in[2];
    const float* w_proj = (const float*)d_in[3];
    const float* b_proj = (const float*)d_in[4];
    float* out = (float*)d_out;

    char* ws = (char*)d_ws;
    __bf16* qkb    = (__bf16*)ws;                                   // 8192 x 2048
    __bf16* vTb    = qkb + (size_t)M_ROWS * 2048;                   // 64 x 64 x 2048
    __bf16* xb     = vTb + (size_t)NH * B_SZ * HD * T_SEQ;          // 8192 x 1024
    __bf16* wqkvT  = xb + (size_t)M_ROWS * D_MODEL;                 // 3072 x 1024
    __bf16* wprojT = wqkvT + (size_t)N_QKV * D_MODEL;               // 1024 x 1024
    __bf16* aout   = wprojT + (size_t)D_MODEL * D_MODEL;            // 8192 x 1024

    cvt_bf16<<<dim3(M_ROWS * D_MODEL / 8 / 256), 256, 0, stream>>>(
        x, xb, M_ROWS * D_MODEL / 8);
    transpose_cvt<<<dim3(N_QKV / 32, D_MODEL / 32), 256, 0, stream>>>(
        w_qkv, wqkvT, D_MODEL, N_QKV);
    transpose_cvt<<<dim3(D_MODEL / 32, D_MODEL / 32), 256, 0, stream>>>(
        w_proj, wprojT, D_MODEL, D_MODEL);

    gemm_mfma<1><<<dim3((M_ROWS / 128) * (N_QKV / 128)), 256, 0, stream>>>(
        xb, wqkvT, b_qkv, qkb, vTb, M_ROWS, N_QKV, D_MODEL);

    attn_mfma<<<dim3(B_SZ * NH * 16), 256, 0, stream>>>(qkb, vTb, aout);

    gemm_mfma<0><<<dim3((M_ROWS / 128) * (D_MODEL / 128)), 256, 0, stream>>>(
        aout, wprojT, b_proj, out, nullptr, M_ROWS, D_MODEL, D_MODEL);
}

// Round 14
// 188.002 us; speedup vs baseline: 1.2903x; 1.0358x over previous
//
#include <hip/hip_runtime.h>
#include <hip/hip_bf16.h>
#include <math.h>

#define D_MODEL 1024
#define NH      16
#define HD      64
#define T_SEQ   2048
#define B_SZ    4
#define M_ROWS  (B_SZ * T_SEQ)       // 8192
#define N_QKV   (3 * D_MODEL)        // 3072

typedef __bf16 bf16x8 __attribute__((ext_vector_type(8)));
typedef __bf16 bf16x4 __attribute__((ext_vector_type(4)));
typedef float  f32x4  __attribute__((ext_vector_type(4)));

__device__ __forceinline__ bf16x8 cvt8(float4 a, float4 b) {
    bf16x8 v;
    v[0]=(__bf16)a.x; v[1]=(__bf16)a.y; v[2]=(__bf16)a.z; v[3]=(__bf16)a.w;
    v[4]=(__bf16)b.x; v[5]=(__bf16)b.y; v[6]=(__bf16)b.z; v[7]=(__bf16)b.w;
    return v;
}

__device__ __forceinline__ void gload_lds16(const __bf16* g, __bf16* l) {
    __builtin_amdgcn_global_load_lds(
        (const __attribute__((address_space(1))) void*)g,
        (__attribute__((address_space(3))) void*)l, 16, 0, 0);
}

// raw v_exp_f32: computes 2^x (input already in log2 units)
__device__ __forceinline__ float exp2v(float x) {
    float r;
    asm("v_exp_f32 %0, %1" : "=v"(r) : "v"(x));
    return r;
}

// ---------------------------------------------------------------------------
// Fused prep: region A = fp32->bf16 convert of x (blocks [0,4096));
// region B = transpose-convert w_qkv (blocks [4096,7168));
// region C = transpose-convert w_proj (blocks [7168,8192)).
// Region A returns before the barrier; B/C execute it block-uniformly (legal).
// ---------------------------------------------------------------------------
__global__ __launch_bounds__(256) void prep_fused(
    const float* __restrict__ x, const float* __restrict__ w_qkv,
    const float* __restrict__ w_proj, __bf16* __restrict__ xb,
    __bf16* __restrict__ wqkvT, __bf16* __restrict__ wprojT)
{
    const int bid = blockIdx.x;
    if (bid < 4096) {                       // ---- region A: cvt x ----
        const int i = bid * 256 + threadIdx.x;   // i < 1048576 exactly
        float4 a = ((const float4*)x)[2 * i];
        float4 b = ((const float4*)x)[2 * i + 1];
        ((bf16x8*)xb)[i] = cvt8(a, b);
        return;
    }

    __shared__ float t[32][33];
    const float* W; __bf16* WT; int C, tb;
    if (bid < 7168) { tb = bid - 4096; W = w_qkv;  WT = wqkvT;  C = N_QKV;   }
    else            { tb = bid - 7168; W = w_proj; WT = wprojT; C = D_MODEL; }
    const int nbx = C >> 5;
    const int by = tb / nbx, bx = tb - by * nbx;
    const int tr0 = by * 32, tc0 = bx * 32;      // rows in [0,1024), cols in [0,C)
    const int lr = threadIdx.x >> 5, lc = threadIdx.x & 31;
    #pragma unroll
    for (int i = 0; i < 4; ++i)
        t[lr + i * 8][lc] = W[(size_t)(tr0 + lr + i * 8) * C + tc0 + lc];
    __syncthreads();
    #pragma unroll
    for (int i = 0; i < 4; ++i)
        WT[(size_t)(tc0 + lr + i * 8) * D_MODEL + tr0 + lc] = (__bf16)t[lc][lr + i * 8];
}

// ---------------------------------------------------------------------------
// bf16 MFMA GEMM (unchanged): 128x128 tile, BK=64, both-sides XOR swizzle.
// ---------------------------------------------------------------------------
template<int MODE>
__global__ __launch_bounds__(256) void gemm_mfma(
    const __bf16* __restrict__ A, const __bf16* __restrict__ BT,
    const float* __restrict__ bias, void* __restrict__ C0,
    __bf16* __restrict__ vT, int M, int N, int K)
{
    __shared__ __bf16 As[128 * 64];
    __shared__ __bf16 Bs[128 * 64];

    const int nbn = N >> 7;
    const int nwg = gridDim.x;
    int bid = blockIdx.x;
    bid = (bid & 7) * (nwg >> 3) + (bid >> 3);       // XCD swizzle (nwg % 8 == 0)
    const int tm = bid / nbn, tn = bid % nbn;
    const int row0 = tm << 7, col0 = tn << 7;

    const int tid  = threadIdx.x;
    const int wid  = tid >> 6, lane = tid & 63;
    const int wm   = wid >> 1, wn = wid & 1;
    const int g    = lane >> 4, r16 = lane & 15;

    f32x4 acc[4][4] = {};

    for (int k0 = 0; k0 < K; k0 += 64) {
        #pragma unroll
        for (int i = 0; i < 4; ++i) {
            const int seg = wid * 4 + i;                 // 0..15
            const int row = seg * 8 + (lane >> 3);       // 0..127
            const int kel = ((lane & 7) * 8) ^ ((row & 7) * 8);
            gload_lds16(A  + (size_t)(row0 + row) * K + k0 + kel, As + seg * 512);
            gload_lds16(BT + (size_t)(col0 + row) * K + k0 + kel, Bs + seg * 512);
        }
        __syncthreads();

        #pragma unroll
        for (int kk = 0; kk < 2; ++kk) {
            bf16x8 af[4], bfr[4];
            #pragma unroll
            for (int mt = 0; mt < 4; ++mt) {
                const int row = wm * 64 + mt * 16 + r16;
                af[mt] = *(const bf16x8*)((const char*)As + row * 128
                             + ((kk * 64 + g * 16) ^ ((row & 7) << 4)));
            }
            #pragma unroll
            for (int nt = 0; nt < 4; ++nt) {
                const int row = wn * 64 + nt * 16 + r16;
                bfr[nt] = *(const bf16x8*)((const char*)Bs + row * 128
                             + ((kk * 64 + g * 16) ^ ((row & 7) << 4)));
            }
            #pragma unroll
            for (int mt = 0; mt < 4; ++mt)
                #pragma unroll
                for (int nt = 0; nt < 4; ++nt)
                    acc[mt][nt] = __builtin_amdgcn_mfma_f32_16x16x32_bf16(
                        af[mt], bfr[nt], acc[mt][nt], 0, 0, 0);
        }
        __syncthreads();
    }

    const bool isV = (MODE == 1) && (tn >= 16);

    #pragma unroll
    for (int mt = 0; mt < 4; ++mt) {
        #pragma unroll
        for (int nt = 0; nt < 4; ++nt) {
            const int col = col0 + wn * 64 + nt * 16 + r16;
            const float bv = bias[col];
            const int rowb = row0 + wm * 64 + mt * 16 + g * 4;
            if (MODE == 0) {
                #pragma unroll
                for (int j = 0; j < 4; ++j)
                    ((float*)C0)[(size_t)(rowb + j) * N + col] = acc[mt][nt][j] + bv;
            } else if (!isV) {
                #pragma unroll
                for (int j = 0; j < 4; ++j)
                    ((__bf16*)C0)[(size_t)(rowb + j) * 2048 + col] =
                        (__bf16)(acc[mt][nt][j] + bv);
            } else {
                const int hh = (col - 2048) >> 6, dd = (col - 2048) & 63;
                const int bb = rowb >> 11, tt = rowb & 2047;
                __bf16 p4[4];
                #pragma unroll
                for (int j = 0; j < 4; ++j) p4[j] = (__bf16)(acc[mt][nt][j] + bv);
                *(bf16x4*)&vT[((size_t)((bb * NH + hh) * HD + dd)) * T_SEQ + tt]
                    = *(const bf16x4*)p4;
            }
        }
    }
}

// ---------------------------------------------------------------------------
// MFMA flash attention v3.3 (unchanged from R13 = best verified, 92.6us).
// Block = 4 waves = one 128-row q-strip; wave owns 32 q-rows.  Grid 1024;
// balanced qt LUT; waves 0/1 stage K/V with the 0-conflict mapping.
// Defer-max (log2 units) + exp2; lane-partial lrow; masked-tile skip.
// ---------------------------------------------------------------------------
__global__ __launch_bounds__(256) void attn_mfma(
    const __bf16* __restrict__ qkb, const __bf16* __restrict__ vT,
    __bf16* __restrict__ aout)
{
    const int idx  = blockIdx.x;            // 0..1023
    const int slot = idx >> 6;
    const int j    = slot & 3, p = slot >> 2;
    const int qt   = (p == 0) ? 15 - j : (p == 1) ? 8 + j : (p == 2) ? 4 + j : 3 - j;
    const int bh   = idx & 63;
    const int b    = bh >> 4;
    const int h    = bh & 15;
    const int tid  = threadIdx.x;
    const int wid  = tid >> 6;
    const int lane = tid & 63;
    const int g    = lane >> 4;
    const int n    = lane & 15;
    const int swzn = (n & 7) << 4;

    const int q0    = qt * 128;
    const int qbase = q0 + wid * 32;
    const int nkt   = 2 * qt + 2;

    __shared__ __align__(16) char Ks[64 * 128];        // [kv][d]
    __shared__ __align__(16) char Vs[64 * 128];        // [d][kv]
    __shared__ __align__(16) char Ps[4][32 * 128];     // per-wave [q][kv]

    const bool stager = (tid < 128);
    const int  srow   = (tid >> 1) & 63;    // 0..63
    const int  sch2   = tid & 1;            // half selector
    const int  swzw   = (srow & 7) << 4;

    const float qscale = 0.125f * 1.44269504089f;
    bf16x8 qa[2][2];
    #pragma unroll
    for (int rb = 0; rb < 2; ++rb) {
        const size_t qrow = (size_t)(b * T_SEQ + qbase + rb * 16 + n) * 2048
                            + (size_t)h * HD;
        qa[rb][0] = *(const bf16x8*)&qkb[qrow + g * 8];
        qa[rb][1] = *(const bf16x8*)&qkb[qrow + 32 + g * 8];
        #pragma unroll
        for (int jj = 0; jj < 8; ++jj) {
            qa[rb][0][jj] = (__bf16)((float)qa[rb][0][jj] * qscale);
            qa[rb][1][jj] = (__bf16)((float)qa[rb][1][jj] * qscale);
        }
    }

    f32x4 o[2][4] = {};
    float mrow[2][4] = {};                  // defer-max base m=0 (log2 units)
    float lrow[2][4] = {};                  // lane-partial row sums

    const __bf16* gK = qkb + (size_t)(b * T_SEQ + srow) * 2048 + 1024
                       + (size_t)h * HD + sch2 * 32;
    const __bf16* gV = vT + ((size_t)((b * NH + h) * HD + srow)) * T_SEQ + sch2 * 32;

    bf16x8 kreg[4] = {}, vreg[4] = {};
    if (stager) {
        #pragma unroll
        for (int c = 0; c < 4; ++c) {
            kreg[c] = *(const bf16x8*)(gK + c * 8);
            vreg[c] = *(const bf16x8*)(gV + c * 8);
        }
    }

    for (int kt = 0; kt < nkt; ++kt) {
        if (stager) {
            #pragma unroll
            for (int c = 0; c < 4; ++c) {
                const int boff = (sch2 * 64 + c * 16) ^ swzw;
                *(bf16x8*)(Ks + srow * 128 + boff) = kreg[c];
                *(bf16x8*)(Vs + srow * 128 + boff) = vreg[c];
            }
        }
        __syncthreads();

        if (stager && kt + 1 < nkt) {
            const size_t kb2 = (size_t)(kt + 1) * 64;
            #pragma unroll
            for (int c = 0; c < 4; ++c) {
                kreg[c] = *(const bf16x8*)(gK + kb2 * 2048 + c * 8);
                vreg[c] = *(const bf16x8*)(gV + kb2 + c * 8);
            }
        }

        const int kb0 = kt * 64;
        const bool active = (kb0 <= qbase + 31);    // wave-uniform

        if (active) {
            f32x4 s4[2][4] = {};
            __builtin_amdgcn_s_setprio(1);
            #pragma unroll
            for (int cc = 0; cc < 2; ++cc) {
                bf16x8 kf[4];
                #pragma unroll
                for (int sub = 0; sub < 4; ++sub)
                    kf[sub] = *(const bf16x8*)(Ks + (sub * 16 + n) * 128
                                               + ((cc * 64 + g * 16) ^ swzn));
                #pragma unroll
                for (int rb = 0; rb < 2; ++rb)
                    #pragma unroll
                    for (int sub = 0; sub < 4; ++sub)
                        s4[rb][sub] = __builtin_amdgcn_mfma_f32_16x16x32_bf16(
                            qa[rb][cc], kf[sub], s4[rb][sub], 0, 0, 0);
            }
            __builtin_amdgcn_s_setprio(0);

            const bool needmask = (kb0 + 63 > qbase);   // wave-uniform

            #pragma unroll
            for (int rb = 0; rb < 2; ++rb) {
                if (needmask) {
                    #pragma unroll
                    for (int r = 0; r < 4; ++r) {
                        const int qrow = qbase + rb * 16 + 4 * g + r;
                        #pragma unroll
                        for (int sub = 0; sub < 4; ++sub)
                            if (kb0 + sub * 16 + n > qrow) s4[rb][sub][r] = -INFINITY;
                    }
                }
                float pm[4];
                int ok = 1;
                #pragma unroll
                for (int r = 0; r < 4; ++r) {
                    pm[r] = fmaxf(fmaxf(s4[rb][0][r], s4[rb][1][r]),
                                  fmaxf(s4[rb][2][r], s4[rb][3][r]));
                    ok &= (pm[r] <= mrow[rb][r] + 8.f);
                }
                if (__all(ok)) {
                    #pragma unroll
                    for (int r = 0; r < 4; ++r) {
                        const float m = mrow[rb][r];
                        const float p0 = exp2v(s4[rb][0][r] - m);
                        const float p1 = exp2v(s4[rb][1][r] - m);
                        const float p2 = exp2v(s4[rb][2][r] - m);
                        const float p3 = exp2v(s4[rb][3][r] - m);
                        lrow[rb][r] += (p0 + p1) + (p2 + p3);
                        char* prow = Ps[wid] + (rb * 16 + 4 * g + r) * 128;
                        const int pswz = ((4 * g + r) & 7) << 4;
                        *(__bf16*)(prow + ((2 * n)      ^ pswz)) = (__bf16)p0;
                        *(__bf16*)(prow + ((2 * n + 32) ^ pswz)) = (__bf16)p1;
                        *(__bf16*)(prow + ((2 * n + 64) ^ pswz)) = (__bf16)p2;
                        *(__bf16*)(prow + ((2 * n + 96) ^ pswz)) = (__bf16)p3;
                    }
                } else {
                    #pragma unroll
                    for (int r = 0; r < 4; ++r) {
                        float tm = pm[r];
                        #pragma unroll
                        for (int off = 1; off < 16; off <<= 1)
                            tm = fmaxf(tm, __shfl_xor(tm, off));
                        const float mnew = fmaxf(mrow[rb][r], tm);
                        const float corr = exp2v(mrow[rb][r] - mnew);
                        mrow[rb][r] = mnew;
                        const float p0 = exp2v(s4[rb][0][r] - mnew);
                        const float p1 = exp2v(s4[rb][1][r] - mnew);
                        const float p2 = exp2v(s4[rb][2][r] - mnew);
                        const float p3 = exp2v(s4[rb][3][r] - mnew);
                        lrow[rb][r] = lrow[rb][r] * corr + (p0 + p1) + (p2 + p3);
                        #pragma unroll
                        for (int nt = 0; nt < 4; ++nt) o[rb][nt][r] *= corr;
                        char* prow = Ps[wid] + (rb * 16 + 4 * g + r) * 128;
                        const int pswz = ((4 * g + r) & 7) << 4;
                        *(__bf16*)(prow + ((2 * n)      ^ pswz)) = (__bf16)p0;
                        *(__bf16*)(prow + ((2 * n + 32) ^ pswz)) = (__bf16)p1;
                        *(__bf16*)(prow + ((2 * n + 64) ^ pswz)) = (__bf16)p2;
                        *(__bf16*)(prow + ((2 * n + 96) ^ pswz)) = (__bf16)p3;
                    }
                }
            }

            __builtin_amdgcn_s_setprio(1);
            #pragma unroll
            for (int cc = 0; cc < 2; ++cc) {
                bf16x8 vf[4];
                #pragma unroll
                for (int nt = 0; nt < 4; ++nt)
                    vf[nt] = *(const bf16x8*)(Vs + (nt * 16 + n) * 128
                                              + ((cc * 64 + g * 16) ^ swzn));
                #pragma unroll
                for (int rb = 0; rb < 2; ++rb) {
                    bf16x8 pa = *(const bf16x8*)(Ps[wid] + (rb * 16 + n) * 128
                                                 + ((cc * 64 + g * 16) ^ swzn));
                    #pragma unroll
                    for (int nt = 0; nt < 4; ++nt)
                        o[rb][nt] = __builtin_amdgcn_mfma_f32_16x16x32_bf16(
                            pa, vf[nt], o[rb][nt], 0, 0, 0);
                }
            }
            __builtin_amdgcn_s_setprio(0);
        }
        __syncthreads();
    }

    #pragma unroll
    for (int rb = 0; rb < 2; ++rb) {
        float inv[4];
        #pragma unroll
        for (int r = 0; r < 4; ++r) {
            float ssum = lrow[rb][r];
            #pragma unroll
            for (int off = 1; off < 16; off <<= 1)
                ssum += __shfl_xor(ssum, off);
            inv[r] = 1.f / ssum;
        }
        const size_t obase = (size_t)(b * T_SEQ + qbase + rb * 16) * D_MODEL
                             + (size_t)h * HD;
        #pragma unroll
        for (int nt = 0; nt < 4; ++nt)
            #pragma unroll
            for (int r = 0; r < 4; ++r)
                aout[obase + (size_t)(4 * g + r) * D_MODEL + nt * 16 + n]
                    = (__bf16)(o[rb][nt][r] * inv[r]);
    }
}

// ---------------------------------------------------------------------------
extern "C" void kernel_launch(void* const* d_in, const int* in_sizes, int n_in,
                              void* d_out, int out_size, void* d_ws, size_t ws_size,
                              hipStream_t stream)
{
    const float* x      = (const float*)d_in[0];
    const float* w_qkv  = (const float*)d_in[1];
    const float* b_qkv  = (const float*)d_in[2];
    const float* w_proj = (const float*)d_in[3];
    const float* b_proj = (const float*)d_in[4];
    float* out = (float*)d_out;

    char* ws = (char*)d_ws;
    __bf16* qkb    = (__bf16*)ws;                                   // 8192 x 2048
    __bf16* vTb    = qkb + (size_t)M_ROWS * 2048;                   // 64 x 64 x 2048
    __bf16* xb     = vTb + (size_t)NH * B_SZ * HD * T_SEQ;          // 8192 x 1024
    __bf16* wqkvT  = xb + (size_t)M_ROWS * D_MODEL;                 // 3072 x 1024
    __bf16* wprojT = wqkvT + (size_t)N_QKV * D_MODEL;               // 1024 x 1024
    __bf16* aout   = wprojT + (size_t)D_MODEL * D_MODEL;            // 8192 x 1024

    // fused prep: 4096 (cvt x) + 3072 (w_qkv^T) + 1024 (w_proj^T) blocks
    prep_fused<<<dim3(8192), 256, 0, stream>>>(x, w_qkv, w_proj, xb, wqkvT, wprojT);

    gemm_mfma<1><<<dim3((M_ROWS / 128) * (N_QKV / 128)), 256, 0, stream>>>(
        xb, wqkvT, b_qkv, qkb, vTb, M_ROWS, N_QKV, D_MODEL);

    attn_mfma<<<dim3(B_SZ * NH * 16), 256, 0, stream>>>(qkb, vTb, aout);

    gemm_mfma<0><<<dim3((M_ROWS / 128) * (D_MODEL / 128)), 256, 0, stream>>>(
        aout, wprojT, b_proj, out, nullptr, M_ROWS, D_MODEL, D_MODEL);
}